// Round 14
// baseline (673.045 us; speedup 1.0000x reference)
//
#include <hip/hip_runtime.h>

#define H 16
#define C 10
#define G_GRAPHS 1024

#define BSH 10                    // bucket shift: 1024 nodes per bucket
#define BNODES 1024
#define BKB 512                   // bucket slots (actual = ceil(N/1024) = 489)
#define CAP 18432                 // per-bucket edge capacity (mean 16384, ~16 sigma)
#define BIN_T 1024
#define BIN_EPT 8
#define TILE (BIN_T * BIN_EPT)    // 8192 edges per bin block
#define POOLW 8                   // LDS pooled-graph window in k_g2

__device__ __forceinline__ float bf_lo(unsigned v) { return __uint_as_float(v << 16); }
__device__ __forceinline__ float bf_hi(unsigned v) { return __uint_as_float(v & 0xffff0000u); }
__device__ __forceinline__ unsigned short f2bf(float f) {
    unsigned u = __float_as_uint(f);
    return (unsigned short)((u + 0x7fffu + ((u >> 16) & 1u)) >> 16);  // RNE
}

// ---- init: bucket cursors + pooled zeros (deg zeroed via hipMemsetAsync) ----
__global__ void k_init(int* __restrict__ cursor, float* __restrict__ pooled) {
    int i = blockIdx.x * blockDim.x + threadIdx.x;
    if (i < BKB) cursor[i] = i * CAP;
    if (i < G_GRAPHS * H) pooled[i] = 0.0f;
}

// ---- staged multisplit + fused per-node degree count (global atomics, 2 MB array) ----
__global__ void __launch_bounds__(1024, 2)
k_bin(const int4* __restrict__ src4, const int4* __restrict__ dst4,
      int* __restrict__ cursor, unsigned* __restrict__ packed,
      int* __restrict__ deg, int E4) {
    __shared__ int h[BKB];
    __shared__ int sc[BKB];
    __shared__ int of[BKB];
    __shared__ int ab[BKB];
    __shared__ int wsum[8];
    __shared__ unsigned stage[TILE];          // 32 KB
    __shared__ unsigned short sbk[TILE];      // 16 KB
    int tid = threadIdx.x;
    int wave = tid >> 6, lane = tid & 63;
    if (tid < BKB) h[tid] = 0;
    __syncthreads();
    long base4 = (long)blockIdx.x * (TILE / 4);
    unsigned pk[BIN_EPT];
    short bk[BIN_EPT];
#pragma unroll
    for (int k = 0; k < BIN_EPT / 4; k++) {
        long i4 = base4 + (long)k * BIN_T + tid;
        if (i4 < E4) {
            int4 s = src4[i4];
            int4 d = dst4[i4];
            unsigned s0 = (unsigned)s.x, s1 = (unsigned)s.y, s2 = (unsigned)s.z, s3 = (unsigned)s.w;
            unsigned d0 = (unsigned)d.x, d1 = (unsigned)d.y, d2 = (unsigned)d.z, d3 = (unsigned)d.w;
            pk[k * 4 + 0] = (s0 << BSH) | (d0 & (BNODES - 1)); bk[k * 4 + 0] = (short)(d0 >> BSH);
            pk[k * 4 + 1] = (s1 << BSH) | (d1 & (BNODES - 1)); bk[k * 4 + 1] = (short)(d1 >> BSH);
            pk[k * 4 + 2] = (s2 << BSH) | (d2 & (BNODES - 1)); bk[k * 4 + 2] = (short)(d2 >> BSH);
            pk[k * 4 + 3] = (s3 << BSH) | (d3 & (BNODES - 1)); bk[k * 4 + 3] = (short)(d3 >> BSH);
            atomicAdd(&h[bk[k * 4 + 0]], 1);
            atomicAdd(&h[bk[k * 4 + 1]], 1);
            atomicAdd(&h[bk[k * 4 + 2]], 1);
            atomicAdd(&h[bk[k * 4 + 3]], 1);
            atomicAdd(&deg[d0], 1);           // fused degree histogram
            atomicAdd(&deg[d1], 1);
            atomicAdd(&deg[d2], 1);
            atomicAdd(&deg[d3], 1);
        } else {
            bk[k * 4 + 0] = -1; bk[k * 4 + 1] = -1; bk[k * 4 + 2] = -1; bk[k * 4 + 3] = -1;
        }
    }
    __syncthreads();
    // wave-shuffle inclusive scan of h[0..BKB)
    int v = (tid < BKB) ? h[tid] : 0;
    int xs = v;
#pragma unroll
    for (int off = 1; off < 64; off <<= 1) {
        int t = __shfl_up(xs, off, 64);
        if (lane >= off) xs += t;
    }
    if (lane == 63 && wave < BKB / 64) wsum[wave] = xs;
    __syncthreads();
    if (tid < BKB) {
        int woff = 0;
        for (int i = 0; i < wave; i++) woff += wsum[i];
        int incl = xs + woff;
        sc[tid] = incl;
        int excl = incl - v;
        int gb = 0;
        if (v > 0) gb = atomicAdd(&cursor[tid], v);   // one reservation per (block,bucket)
        of[tid] = excl;
        ab[tid] = gb - excl;
    }
    __syncthreads();
#pragma unroll
    for (int k = 0; k < BIN_EPT; k++) {
        if (bk[k] >= 0) {
            int pos = atomicAdd(&of[bk[k]], 1);
            stage[pos] = pk[k];
            sbk[pos] = (unsigned short)bk[k];
        }
    }
    __syncthreads();
    int total = sc[BKB - 1];
    for (int i = tid; i < total; i += BIN_T)
        packed[ab[sbk[i]] + i] = stage[i];    // contiguous per-bucket runs
}

// ---- k_pre: per-bucket wave-scan of deg -> row_start; dis; bf16 xs. (~12 MB traffic) ----
__global__ void __launch_bounds__(1024, 2)
k_pre(const int* __restrict__ deg, const float* __restrict__ x,
      int* __restrict__ row_start, float* __restrict__ dis,
      unsigned* __restrict__ xsb, int N) {
    __shared__ int wsum[16];
    int tid = threadIdx.x;   // 1024
    int wave = tid >> 6, lane = tid & 63;
    int b = blockIdx.x;
    int node = (b << BSH) + tid;
    int v = (node < N) ? deg[node] : 0;
    int xs = v;
#pragma unroll
    for (int off = 1; off < 64; off <<= 1) {
        int t = __shfl_up(xs, off, 64);
        if (lane >= off) xs += t;
    }
    if (lane == 63) wsum[wave] = xs;
    __syncthreads();
    int woff = 0;
    for (int i = 0; i < wave; i++) woff += wsum[i];
    if (node < N) {
        row_start[node] = b * CAP + (xs + woff - v);
        float dn = rsqrtf((float)(v + 1));
        dis[node] = dn;
        float2 xv = ((const float2*)x)[node];
        xsb[node] = (unsigned)f2bf(xv.x * dn) | ((unsigned)f2bf(xv.y * dn) << 16);
    }
}

// ---- csrB: scatter packed -> node-ordered csr, fused layer-1 LDS agg + epilogue ----
__global__ void __launch_bounds__(1024, 2)
k_csrB(const unsigned* __restrict__ packed, const int* __restrict__ cursor,
       const int* __restrict__ row_start, const unsigned* __restrict__ xsb,
       const float* __restrict__ dis, const float* __restrict__ W1,
       const float* __restrict__ b1, const float* __restrict__ W2,
       int* __restrict__ csr, uint4* __restrict__ Ah4, int N) {
    __shared__ int cur[BNODES];
    __shared__ float accx[BNODES];
    __shared__ float accy[BNODES];
    __shared__ float w1s[2 * H];
    __shared__ float b1s[H];
    __shared__ float w2s[H * H];
    int tid = threadIdx.x;   // 1024
    if (tid < 2 * H) w1s[tid] = W1[tid];
    if (tid < H) b1s[tid] = b1[tid];
    if (tid < H * H) w2s[tid] = W2[tid];
    int b = blockIdx.x;
    int base = b * CAP;
    int cnt = cursor[b] - base;
    int node = (b << BSH) + tid;
    cur[tid] = (node < N) ? (row_start[node] - base) : 0;
    accx[tid] = 0.0f;
    accy[tid] = 0.0f;
    __syncthreads();
    for (int i = tid; i < cnt; i += 1024) {
        unsigned p = packed[base + i];
        int l = (int)(p & (BNODES - 1));
        int s = (int)(p >> BSH);
        int pos = atomicAdd(&cur[l], 1);
        csr[base + pos] = s;                  // 72 KB window -> L2-resident writes
        unsigned v = xsb[s];                  // 4 B random read, L2-resident (2 MB)
        atomicAdd(&accx[l], bf_lo(v));
        atomicAdd(&accy[l], bf_hi(v));
    }
    __syncthreads();
    if (node < N) {
        unsigned xn = xsb[node];
        float sx = accx[tid] + bf_lo(xn);
        float sy = accy[tid] + bf_hi(xn);
        float dn = dis[node];
        float h1[H];
#pragma unroll
        for (int j = 0; j < H; j++)
            h1[j] = fmaxf(dn * (sx * w1s[j] + sy * w1s[H + j]) + b1s[j], 0.0f);
        unsigned o[8];
#pragma unroll
        for (int j2 = 0; j2 < 8; j2++) {
            float alo = 0.0f, ahi = 0.0f;
#pragma unroll
            for (int k = 0; k < H; k++) {
                alo += h1[k] * w2s[k * H + 2 * j2 + 0];
                ahi += h1[k] * w2s[k * H + 2 * j2 + 1];
            }
            o[j2] = (unsigned)f2bf(alo * dn) | ((unsigned)f2bf(ahi * dn) << 16);
        }
        Ah4[node * 2 + 0] = make_uint4(o[0], o[1], o[2], o[3]);
        Ah4[node * 2 + 1] = make_uint4(o[4], o[5], o[6], o[7]);
    }
}

// ---- gather layer 2 (round-12 optimum): 4 lanes/edge, uint2, relu + LDS pool ----
__global__ void __launch_bounds__(256, 8)
k_g2(const int* __restrict__ csr, const int* __restrict__ row_start,
     const int* __restrict__ deg, const uint2* __restrict__ Ah2,
     const float* __restrict__ dis, const float* __restrict__ b2,
     const int* __restrict__ batch, float* __restrict__ pooled, int N) {
    __shared__ int pool_s[POOLW * H];     // int-as-float max tile, values >= 0
    __shared__ int gbase_s;
    int tid = threadIdx.x;
    int node0 = blockIdx.x * 64;
    if (tid == 0) gbase_s = batch[node0 < N ? node0 : (N - 1)];
    if (tid < POOLW * H) pool_s[tid] = 0;
    __syncthreads();
    int node = node0 + (tid >> 2);
    int l = tid & 3;                      // lane covers features 4l .. 4l+3
    if (node < N) {
        int st = row_start[node];
        int d = deg[node];
        float a0 = 0.f, a1 = 0.f, a2 = 0.f, a3 = 0.f;
        int k = 0;
        for (; k + 8 <= d; k += 8) {
            int s0 = csr[st + k],     s1 = csr[st + k + 1], s2 = csr[st + k + 2], s3 = csr[st + k + 3];
            int s4 = csr[st + k + 4], s5 = csr[st + k + 5], s6 = csr[st + k + 6], s7 = csr[st + k + 7];
            uint2 v0 = Ah2[s0 * 4 + l], v1 = Ah2[s1 * 4 + l], v2 = Ah2[s2 * 4 + l], v3 = Ah2[s3 * 4 + l];
            uint2 v4 = Ah2[s4 * 4 + l], v5 = Ah2[s5 * 4 + l], v6 = Ah2[s6 * 4 + l], v7 = Ah2[s7 * 4 + l];
            a0 += ((bf_lo(v0.x) + bf_lo(v1.x)) + (bf_lo(v2.x) + bf_lo(v3.x))) +
                  ((bf_lo(v4.x) + bf_lo(v5.x)) + (bf_lo(v6.x) + bf_lo(v7.x)));
            a1 += ((bf_hi(v0.x) + bf_hi(v1.x)) + (bf_hi(v2.x) + bf_hi(v3.x))) +
                  ((bf_hi(v4.x) + bf_hi(v5.x)) + (bf_hi(v6.x) + bf_hi(v7.x)));
            a2 += ((bf_lo(v0.y) + bf_lo(v1.y)) + (bf_lo(v2.y) + bf_lo(v3.y))) +
                  ((bf_lo(v4.y) + bf_lo(v5.y)) + (bf_lo(v6.y) + bf_lo(v7.y)));
            a3 += ((bf_hi(v0.y) + bf_hi(v1.y)) + (bf_hi(v2.y) + bf_hi(v3.y))) +
                  ((bf_hi(v4.y) + bf_hi(v5.y)) + (bf_hi(v6.y) + bf_hi(v7.y)));
        }
        for (; k < d; k++) {
            uint2 v = Ah2[csr[st + k] * 4 + l];
            a0 += bf_lo(v.x); a1 += bf_hi(v.x); a2 += bf_lo(v.y); a3 += bf_hi(v.y);
        }
        uint2 sv = Ah2[node * 4 + l];     // self term
        a0 += bf_lo(sv.x); a1 += bf_hi(sv.x); a2 += bf_lo(sv.y); a3 += bf_hi(sv.y);
        float dn = dis[node];
        int f = 4 * l;
        float h0 = fmaxf(dn * a0 + b2[f + 0], 0.0f);
        float h1 = fmaxf(dn * a1 + b2[f + 1], 0.0f);
        float h2 = fmaxf(dn * a2 + b2[f + 2], 0.0f);
        float h3 = fmaxf(dn * a3 + b2[f + 3], 0.0f);
        int g = batch[node];
        int rel = g - gbase_s;
        if (rel >= 0 && rel < POOLW) {    // sorted batch -> nearly always true
            atomicMax(&pool_s[rel * H + f + 0], __float_as_int(h0));
            atomicMax(&pool_s[rel * H + f + 1], __float_as_int(h1));
            atomicMax(&pool_s[rel * H + f + 2], __float_as_int(h2));
            atomicMax(&pool_s[rel * H + f + 3], __float_as_int(h3));
        } else {
            atomicMax((int*)&pooled[g * H + f + 0], __float_as_int(h0));
            atomicMax((int*)&pooled[g * H + f + 1], __float_as_int(h1));
            atomicMax((int*)&pooled[g * H + f + 2], __float_as_int(h2));
            atomicMax((int*)&pooled[g * H + f + 3], __float_as_int(h3));
        }
    }
    __syncthreads();
    if (tid < POOLW * H) {
        int v = pool_s[tid];
        int g = gbase_s + (tid >> 4);
        if (v != 0 && g < G_GRAPHS)
            atomicMax((int*)&pooled[g * H + (tid & 15)], v);
    }
}

// ---- head: logits = pooled @ Wl + bl, then log_softmax ----
__global__ void k_head(const float* __restrict__ pooled, const float* __restrict__ Wl,
                       const float* __restrict__ bl, float* __restrict__ out) {
    __shared__ float w[H * C];
    __shared__ float b[C];
    int tid = threadIdx.x;
    if (tid < H * C) w[tid] = Wl[tid];
    if (tid < C) b[tid] = bl[tid];
    __syncthreads();
    int g = blockIdx.x * blockDim.x + tid;
    if (g >= G_GRAPHS) return;
    float p[H];
#pragma unroll
    for (int k = 0; k < H; k++) p[k] = fmaxf(pooled[g * H + k], 0.0f);
    float l[C];
    float m = -1e30f;
#pragma unroll
    for (int c = 0; c < C; c++) {
        float acc = b[c];
#pragma unroll
        for (int k = 0; k < H; k++) acc += p[k] * w[k * C + c];
        l[c] = acc;
        m = fmaxf(m, acc);
    }
    float s = 0.0f;
#pragma unroll
    for (int c = 0; c < C; c++) s += expf(l[c] - m);
    float lse = logf(s);
#pragma unroll
    for (int c = 0; c < C; c++) out[g * C + c] = l[c] - m - lse;
}

extern "C" void kernel_launch(void* const* d_in, const int* in_sizes, int n_in,
                              void* d_out, int out_size, void* d_ws, size_t ws_size,
                              hipStream_t stream) {
    const float* x    = (const float*)d_in[0];
    const int*   eidx = (const int*)d_in[1];
    const int*   batch= (const int*)d_in[2];
    const float* W1   = (const float*)d_in[3];
    const float* b1   = (const float*)d_in[4];
    const float* W2   = (const float*)d_in[5];
    const float* b2   = (const float*)d_in[6];
    const float* Wl   = (const float*)d_in[7];
    const float* bl   = (const float*)d_in[8];
    float* out = (float*)d_out;

    int N = in_sizes[0] / 2;
    int E = in_sizes[1] / 2;
    const int* src = eidx;
    const int* dst = eidx + E;

    size_t capBytes  = (size_t)BKB * CAP * sizeof(unsigned); // ~37.7 MB
    char* ws = (char*)d_ws;
    unsigned* packed = (unsigned*)ws;  ws += capBytes;        // live through csrB
    int*   csr       = (int*)ws;       ws += capBytes;
    unsigned short* Ah = (unsigned short*)ws;                 // bf16 [N][16], 16 MB
    ws += (size_t)N * H * sizeof(unsigned short);
    unsigned* xsb    = (unsigned*)ws;  ws += (size_t)N * sizeof(unsigned);
    float* dis       = (float*)ws;     ws += (size_t)N * sizeof(float);
    int*   deg       = (int*)ws;       ws += (size_t)N * sizeof(int);
    int*   row_start = (int*)ws;       ws += (size_t)N * sizeof(int);
    int*   cursor    = (int*)ws;       ws += BKB * sizeof(int);
    float* pooled    = (float*)ws;     ws += (size_t)G_GRAPHS * H * sizeof(float);

    int KB    = (N + BNODES - 1) >> BSH;           // 489 buckets
    int gTile = (E + TILE - 1) / TILE;             // 977 bin blocks
    int gN2   = (N + 63) / 64;                     // 64 nodes / block (layer 2)
    int E4    = E / 4;                             // E is a multiple of 4

    // ---- init + binning (with fused degree count) ----
    hipMemsetAsync(deg, 0, (size_t)N * sizeof(int), stream);
    k_init<<<(G_GRAPHS * H + 255) / 256, 256, 0, stream>>>(cursor, pooled);
    k_bin <<<gTile, BIN_T, 0, stream>>>((const int4*)src, (const int4*)dst, cursor, packed, deg, E4);

    // ---- k_pre: row_start/dis/xsb from deg; csrB: csr scatter + fused layer 1 ----
    k_pre <<<KB, BNODES, 0, stream>>>(deg, x, row_start, dis, xsb, N);
    k_csrB<<<KB, BNODES, 0, stream>>>(packed, cursor, row_start, xsb, dis, W1, b1, W2,
                                      csr, (uint4*)Ah, N);

    // ---- layer 2 (bf16 uint2 gather + LDS pooling) ----
    k_g2  <<<gN2, 256, 0, stream>>>(csr, row_start, deg, (const uint2*)Ah, dis, b2, batch, pooled, N);

    // ---- head ----
    k_head<<<(G_GRAPHS + 255) / 256, 256, 0, stream>>>(pooled, Wl, bl, out);
}

// Round 15
// 382.687 us; speedup vs baseline: 1.7587x; 1.7587x over previous
//
#include <hip/hip_runtime.h>

#define H 16
#define C 10
#define G_GRAPHS 1024

#define BSH 10                    // bucket shift: 1024 nodes per bucket
#define BNODES 1024
#define BKB 512                   // bucket slots (actual = ceil(N/1024) = 489)
#define CAP 18432                 // per-bucket edge capacity (mean 16376, ~16 sigma); %4==0
#define BIN_T 1024
#define BIN_EPT 8
#define TILE (BIN_T * BIN_EPT)    // 8192 edges per bin block
#define POOLW 8                   // LDS pooled-graph window in k_g2

__device__ __forceinline__ float bf_lo(unsigned v) { return __uint_as_float(v << 16); }
__device__ __forceinline__ float bf_hi(unsigned v) { return __uint_as_float(v & 0xffff0000u); }
__device__ __forceinline__ unsigned short f2bf(float f) {
    unsigned u = __float_as_uint(f);
    return (unsigned short)((u + 0x7fffu + ((u >> 16) & 1u)) >> 16);  // RNE
}

// ---- init: bucket cursors + pooled zeros ----
__global__ void k_init(int* __restrict__ cursor, float* __restrict__ pooled) {
    int i = blockIdx.x * blockDim.x + threadIdx.x;
    if (i < BKB) cursor[i] = i * CAP;
    if (i < G_GRAPHS * H) pooled[i] = 0.0f;
}

// ---- staged multisplit with wave-shuffle scan (round-12, known good) ----
__global__ void __launch_bounds__(1024, 2)
k_bin(const int4* __restrict__ src4, const int4* __restrict__ dst4,
      int* __restrict__ cursor, unsigned* __restrict__ packed, int E4) {
    __shared__ int h[BKB];
    __shared__ int sc[BKB];
    __shared__ int of[BKB];
    __shared__ int ab[BKB];
    __shared__ int wsum[8];
    __shared__ unsigned stage[TILE];          // 32 KB
    __shared__ unsigned short sbk[TILE];      // 16 KB
    int tid = threadIdx.x;
    int wave = tid >> 6, lane = tid & 63;
    if (tid < BKB) h[tid] = 0;
    __syncthreads();
    long base4 = (long)blockIdx.x * (TILE / 4);
    unsigned pk[BIN_EPT];
    short bk[BIN_EPT];
#pragma unroll
    for (int k = 0; k < BIN_EPT / 4; k++) {
        long i4 = base4 + (long)k * BIN_T + tid;
        if (i4 < E4) {
            int4 s = src4[i4];
            int4 d = dst4[i4];
            unsigned s0 = (unsigned)s.x, s1 = (unsigned)s.y, s2 = (unsigned)s.z, s3 = (unsigned)s.w;
            unsigned d0 = (unsigned)d.x, d1 = (unsigned)d.y, d2 = (unsigned)d.z, d3 = (unsigned)d.w;
            pk[k * 4 + 0] = (s0 << BSH) | (d0 & (BNODES - 1)); bk[k * 4 + 0] = (short)(d0 >> BSH);
            pk[k * 4 + 1] = (s1 << BSH) | (d1 & (BNODES - 1)); bk[k * 4 + 1] = (short)(d1 >> BSH);
            pk[k * 4 + 2] = (s2 << BSH) | (d2 & (BNODES - 1)); bk[k * 4 + 2] = (short)(d2 >> BSH);
            pk[k * 4 + 3] = (s3 << BSH) | (d3 & (BNODES - 1)); bk[k * 4 + 3] = (short)(d3 >> BSH);
            atomicAdd(&h[bk[k * 4 + 0]], 1);
            atomicAdd(&h[bk[k * 4 + 1]], 1);
            atomicAdd(&h[bk[k * 4 + 2]], 1);
            atomicAdd(&h[bk[k * 4 + 3]], 1);
        } else {
            bk[k * 4 + 0] = -1; bk[k * 4 + 1] = -1; bk[k * 4 + 2] = -1; bk[k * 4 + 3] = -1;
        }
    }
    __syncthreads();
    // wave-shuffle inclusive scan of h[0..BKB) (waves 0..7 hold 64 entries each)
    int v = (tid < BKB) ? h[tid] : 0;
    int xs = v;
#pragma unroll
    for (int off = 1; off < 64; off <<= 1) {
        int t = __shfl_up(xs, off, 64);
        if (lane >= off) xs += t;
    }
    if (lane == 63 && wave < BKB / 64) wsum[wave] = xs;
    __syncthreads();
    if (tid < BKB) {
        int woff = 0;
        for (int i = 0; i < wave; i++) woff += wsum[i];
        int incl = xs + woff;
        sc[tid] = incl;
        int excl = incl - v;
        int gb = 0;
        if (v > 0) gb = atomicAdd(&cursor[tid], v);   // one reservation per (block,bucket)
        of[tid] = excl;
        ab[tid] = gb - excl;
    }
    __syncthreads();
#pragma unroll
    for (int k = 0; k < BIN_EPT; k++) {
        if (bk[k] >= 0) {
            int pos = atomicAdd(&of[bk[k]], 1);
            stage[pos] = pk[k];
            sbk[pos] = (unsigned short)bk[k];
        }
    }
    __syncthreads();
    int total = sc[BKB - 1];
    for (int i = tid; i < total; i += BIN_T)
        packed[ab[sbk[i]] + i] = stage[i];    // contiguous per-bucket runs
}

// ---- csrA: per-bucket histogram (uint4 loads) + wave scan -> deg/row_start/dis/xsb ----
__global__ void __launch_bounds__(1024, 2)
k_csrA(const unsigned* __restrict__ packed, const int* __restrict__ cursor,
       const float* __restrict__ x, int* __restrict__ deg, int* __restrict__ row_start,
       float* __restrict__ dis, unsigned* __restrict__ xsb, int N) {
    __shared__ int lh[BNODES];
    __shared__ int wsum[16];
    int tid = threadIdx.x;   // 1024
    int wave = tid >> 6, lane = tid & 63;
    lh[tid] = 0;
    __syncthreads();
    int b = blockIdx.x;
    int base = b * CAP;
    int cnt = cursor[b] - base;
    const uint4* p4 = (const uint4*)(packed + base);   // base 16B-aligned (CAP%4==0)
    int cnt4 = cnt >> 2;
    for (int i = tid; i < cnt4; i += 1024) {
        uint4 p = p4[i];
        atomicAdd(&lh[p.x & (BNODES - 1)], 1);
        atomicAdd(&lh[p.y & (BNODES - 1)], 1);
        atomicAdd(&lh[p.z & (BNODES - 1)], 1);
        atomicAdd(&lh[p.w & (BNODES - 1)], 1);
    }
    for (int i = (cnt4 << 2) + tid; i < cnt; i += 1024)
        atomicAdd(&lh[packed[base + i] & (BNODES - 1)], 1);
    __syncthreads();
    int v = lh[tid];
    int xs = v;
#pragma unroll
    for (int off = 1; off < 64; off <<= 1) {
        int t = __shfl_up(xs, off, 64);
        if (lane >= off) xs += t;
    }
    if (lane == 63) wsum[wave] = xs;
    __syncthreads();
    int woff = 0;
    for (int i = 0; i < wave; i++) woff += wsum[i];
    int node = (b << BSH) + tid;
    if (node < N) {
        deg[node] = v;
        row_start[node] = base + (xs + woff - v);
        float dn = rsqrtf((float)(v + 1));
        dis[node] = dn;
        float2 xv = ((const float2*)x)[node];
        xsb[node] = (unsigned)f2bf(xv.x * dn) | ((unsigned)f2bf(xv.y * dn) << 16);
    }
}

// ---- csrB: scatter packed (uint4 loads) -> node-ordered csr, fused layer-1 agg ----
__global__ void __launch_bounds__(1024, 2)
k_csrB(const unsigned* __restrict__ packed, const int* __restrict__ cursor,
       const int* __restrict__ row_start, const unsigned* __restrict__ xsb,
       const float* __restrict__ dis, const float* __restrict__ W1,
       const float* __restrict__ b1, const float* __restrict__ W2,
       int* __restrict__ csr, uint4* __restrict__ Ah4, int N) {
    __shared__ int cur[BNODES];
    __shared__ float accx[BNODES];
    __shared__ float accy[BNODES];
    __shared__ float w1s[2 * H];
    __shared__ float b1s[H];
    __shared__ float w2s[H * H];
    int tid = threadIdx.x;   // 1024
    if (tid < 2 * H) w1s[tid] = W1[tid];
    if (tid < H) b1s[tid] = b1[tid];
    if (tid < H * H) w2s[tid] = W2[tid];
    int b = blockIdx.x;
    int base = b * CAP;
    int cnt = cursor[b] - base;
    int node = (b << BSH) + tid;
    cur[tid] = (node < N) ? (row_start[node] - base) : 0;
    accx[tid] = 0.0f;
    accy[tid] = 0.0f;
    __syncthreads();
    const uint4* p4 = (const uint4*)(packed + base);
    int cnt4 = cnt >> 2;
    for (int i = tid; i < cnt4; i += 1024) {
        uint4 p = p4[i];
        unsigned v0 = xsb[p.x >> BSH];        // 4 independent L2-resident reads first
        unsigned v1 = xsb[p.y >> BSH];
        unsigned v2 = xsb[p.z >> BSH];
        unsigned v3 = xsb[p.w >> BSH];
        int l0 = (int)(p.x & (BNODES - 1)), l1 = (int)(p.y & (BNODES - 1));
        int l2 = (int)(p.z & (BNODES - 1)), l3 = (int)(p.w & (BNODES - 1));
        int q0 = atomicAdd(&cur[l0], 1);
        int q1 = atomicAdd(&cur[l1], 1);
        int q2 = atomicAdd(&cur[l2], 1);
        int q3 = atomicAdd(&cur[l3], 1);
        csr[base + q0] = (int)(p.x >> BSH);   // 72 KB window -> L2-resident writes
        csr[base + q1] = (int)(p.y >> BSH);
        csr[base + q2] = (int)(p.z >> BSH);
        csr[base + q3] = (int)(p.w >> BSH);
        atomicAdd(&accx[l0], bf_lo(v0));
        atomicAdd(&accy[l0], bf_hi(v0));
        atomicAdd(&accx[l1], bf_lo(v1));
        atomicAdd(&accy[l1], bf_hi(v1));
        atomicAdd(&accx[l2], bf_lo(v2));
        atomicAdd(&accy[l2], bf_hi(v2));
        atomicAdd(&accx[l3], bf_lo(v3));
        atomicAdd(&accy[l3], bf_hi(v3));
    }
    for (int i = (cnt4 << 2) + tid; i < cnt; i += 1024) {
        unsigned p = packed[base + i];
        int l = (int)(p & (BNODES - 1));
        int s = (int)(p >> BSH);
        int pos = atomicAdd(&cur[l], 1);
        csr[base + pos] = s;
        unsigned v = xsb[s];
        atomicAdd(&accx[l], bf_lo(v));
        atomicAdd(&accy[l], bf_hi(v));
    }
    __syncthreads();
    if (node < N) {
        unsigned xn = xsb[node];
        float sx = accx[tid] + bf_lo(xn);
        float sy = accy[tid] + bf_hi(xn);
        float dn = dis[node];
        float h1[H];
#pragma unroll
        for (int j = 0; j < H; j++)
            h1[j] = fmaxf(dn * (sx * w1s[j] + sy * w1s[H + j]) + b1s[j], 0.0f);
        unsigned o[8];
#pragma unroll
        for (int j2 = 0; j2 < 8; j2++) {
            float alo = 0.0f, ahi = 0.0f;
#pragma unroll
            for (int k = 0; k < H; k++) {
                alo += h1[k] * w2s[k * H + 2 * j2 + 0];
                ahi += h1[k] * w2s[k * H + 2 * j2 + 1];
            }
            o[j2] = (unsigned)f2bf(alo * dn) | ((unsigned)f2bf(ahi * dn) << 16);
        }
        Ah4[node * 2 + 0] = make_uint4(o[0], o[1], o[2], o[3]);
        Ah4[node * 2 + 1] = make_uint4(o[4], o[5], o[6], o[7]);
    }
}

// ---- gather layer 2 (round-12 optimum): 4 lanes/edge, uint2, relu + LDS pool ----
__global__ void __launch_bounds__(256, 8)
k_g2(const int* __restrict__ csr, const int* __restrict__ row_start,
     const int* __restrict__ deg, const uint2* __restrict__ Ah2,
     const float* __restrict__ dis, const float* __restrict__ b2,
     const int* __restrict__ batch, float* __restrict__ pooled, int N) {
    __shared__ int pool_s[POOLW * H];     // int-as-float max tile, values >= 0
    __shared__ int gbase_s;
    int tid = threadIdx.x;
    int node0 = blockIdx.x * 64;
    if (tid == 0) gbase_s = batch[node0 < N ? node0 : (N - 1)];
    if (tid < POOLW * H) pool_s[tid] = 0;
    __syncthreads();
    int node = node0 + (tid >> 2);
    int l = tid & 3;                      // lane covers features 4l .. 4l+3
    if (node < N) {
        int st = row_start[node];
        int d = deg[node];
        float a0 = 0.f, a1 = 0.f, a2 = 0.f, a3 = 0.f;
        int k = 0;
        for (; k + 8 <= d; k += 8) {
            int s0 = csr[st + k],     s1 = csr[st + k + 1], s2 = csr[st + k + 2], s3 = csr[st + k + 3];
            int s4 = csr[st + k + 4], s5 = csr[st + k + 5], s6 = csr[st + k + 6], s7 = csr[st + k + 7];
            uint2 v0 = Ah2[s0 * 4 + l], v1 = Ah2[s1 * 4 + l], v2 = Ah2[s2 * 4 + l], v3 = Ah2[s3 * 4 + l];
            uint2 v4 = Ah2[s4 * 4 + l], v5 = Ah2[s5 * 4 + l], v6 = Ah2[s6 * 4 + l], v7 = Ah2[s7 * 4 + l];
            a0 += ((bf_lo(v0.x) + bf_lo(v1.x)) + (bf_lo(v2.x) + bf_lo(v3.x))) +
                  ((bf_lo(v4.x) + bf_lo(v5.x)) + (bf_lo(v6.x) + bf_lo(v7.x)));
            a1 += ((bf_hi(v0.x) + bf_hi(v1.x)) + (bf_hi(v2.x) + bf_hi(v3.x))) +
                  ((bf_hi(v4.x) + bf_hi(v5.x)) + (bf_hi(v6.x) + bf_hi(v7.x)));
            a2 += ((bf_lo(v0.y) + bf_lo(v1.y)) + (bf_lo(v2.y) + bf_lo(v3.y))) +
                  ((bf_lo(v4.y) + bf_lo(v5.y)) + (bf_lo(v6.y) + bf_lo(v7.y)));
            a3 += ((bf_hi(v0.y) + bf_hi(v1.y)) + (bf_hi(v2.y) + bf_hi(v3.y))) +
                  ((bf_hi(v4.y) + bf_hi(v5.y)) + (bf_hi(v6.y) + bf_hi(v7.y)));
        }
        for (; k < d; k++) {
            uint2 v = Ah2[csr[st + k] * 4 + l];
            a0 += bf_lo(v.x); a1 += bf_hi(v.x); a2 += bf_lo(v.y); a3 += bf_hi(v.y);
        }
        uint2 sv = Ah2[node * 4 + l];     // self term
        a0 += bf_lo(sv.x); a1 += bf_hi(sv.x); a2 += bf_lo(sv.y); a3 += bf_hi(sv.y);
        float dn = dis[node];
        int f = 4 * l;
        float h0 = fmaxf(dn * a0 + b2[f + 0], 0.0f);
        float h1 = fmaxf(dn * a1 + b2[f + 1], 0.0f);
        float h2 = fmaxf(dn * a2 + b2[f + 2], 0.0f);
        float h3 = fmaxf(dn * a3 + b2[f + 3], 0.0f);
        int g = batch[node];
        int rel = g - gbase_s;
        if (rel >= 0 && rel < POOLW) {    // sorted batch -> nearly always true
            atomicMax(&pool_s[rel * H + f + 0], __float_as_int(h0));
            atomicMax(&pool_s[rel * H + f + 1], __float_as_int(h1));
            atomicMax(&pool_s[rel * H + f + 2], __float_as_int(h2));
            atomicMax(&pool_s[rel * H + f + 3], __float_as_int(h3));
        } else {
            atomicMax((int*)&pooled[g * H + f + 0], __float_as_int(h0));
            atomicMax((int*)&pooled[g * H + f + 1], __float_as_int(h1));
            atomicMax((int*)&pooled[g * H + f + 2], __float_as_int(h2));
            atomicMax((int*)&pooled[g * H + f + 3], __float_as_int(h3));
        }
    }
    __syncthreads();
    if (tid < POOLW * H) {
        int v = pool_s[tid];
        int g = gbase_s + (tid >> 4);
        if (v != 0 && g < G_GRAPHS)
            atomicMax((int*)&pooled[g * H + (tid & 15)], v);
    }
}

// ---- head: logits = pooled @ Wl + bl, then log_softmax ----
__global__ void k_head(const float* __restrict__ pooled, const float* __restrict__ Wl,
                       const float* __restrict__ bl, float* __restrict__ out) {
    __shared__ float w[H * C];
    __shared__ float b[C];
    int tid = threadIdx.x;
    if (tid < H * C) w[tid] = Wl[tid];
    if (tid < C) b[tid] = bl[tid];
    __syncthreads();
    int g = blockIdx.x * blockDim.x + tid;
    if (g >= G_GRAPHS) return;
    float p[H];
#pragma unroll
    for (int k = 0; k < H; k++) p[k] = fmaxf(pooled[g * H + k], 0.0f);
    float l[C];
    float m = -1e30f;
#pragma unroll
    for (int c = 0; c < C; c++) {
        float acc = b[c];
#pragma unroll
        for (int k = 0; k < H; k++) acc += p[k] * w[k * C + c];
        l[c] = acc;
        m = fmaxf(m, acc);
    }
    float s = 0.0f;
#pragma unroll
    for (int c = 0; c < C; c++) s += expf(l[c] - m);
    float lse = logf(s);
#pragma unroll
    for (int c = 0; c < C; c++) out[g * C + c] = l[c] - m - lse;
}

extern "C" void kernel_launch(void* const* d_in, const int* in_sizes, int n_in,
                              void* d_out, int out_size, void* d_ws, size_t ws_size,
                              hipStream_t stream) {
    const float* x    = (const float*)d_in[0];
    const int*   eidx = (const int*)d_in[1];
    const int*   batch= (const int*)d_in[2];
    const float* W1   = (const float*)d_in[3];
    const float* b1   = (const float*)d_in[4];
    const float* W2   = (const float*)d_in[5];
    const float* b2   = (const float*)d_in[6];
    const float* Wl   = (const float*)d_in[7];
    const float* bl   = (const float*)d_in[8];
    float* out = (float*)d_out;

    int N = in_sizes[0] / 2;
    int E = in_sizes[1] / 2;
    const int* src = eidx;
    const int* dst = eidx + E;

    size_t capBytes  = (size_t)BKB * CAP * sizeof(unsigned); // ~37.7 MB
    char* ws = (char*)d_ws;
    unsigned* packed = (unsigned*)ws;  ws += capBytes;        // live through csrB
    int*   csr       = (int*)ws;       ws += capBytes;
    unsigned short* Ah = (unsigned short*)ws;                 // bf16 [N][16], 16 MB
    ws += (size_t)N * H * sizeof(unsigned short);
    unsigned* xsb    = (unsigned*)ws;  ws += (size_t)N * sizeof(unsigned);
    float* dis       = (float*)ws;     ws += (size_t)N * sizeof(float);
    int*   deg       = (int*)ws;       ws += (size_t)N * sizeof(int);
    int*   row_start = (int*)ws;       ws += (size_t)N * sizeof(int);
    int*   cursor    = (int*)ws;       ws += BKB * sizeof(int);
    float* pooled    = (float*)ws;     ws += (size_t)G_GRAPHS * H * sizeof(float);

    int KB    = (N + BNODES - 1) >> BSH;           // 489 buckets
    int gTile = (E + TILE - 1) / TILE;             // 977 bin blocks
    int gN2   = (N + 63) / 64;                     // 64 nodes / block (layer 2)
    int E4    = E / 4;                             // E is a multiple of 4

    // ---- init + staged binning ----
    k_init<<<(G_GRAPHS * H + 255) / 256, 256, 0, stream>>>(cursor, pooled);
    k_bin <<<gTile, BIN_T, 0, stream>>>((const int4*)src, (const int4*)dst, cursor, packed, E4);

    // ---- csrA: degrees/scan/dis/xs; csrB: csr scatter + fused layer 1 -> Ah ----
    k_csrA<<<KB, BNODES, 0, stream>>>(packed, cursor, x, deg, row_start, dis, xsb, N);
    k_csrB<<<KB, BNODES, 0, stream>>>(packed, cursor, row_start, xsb, dis, W1, b1, W2,
                                      csr, (uint4*)Ah, N);

    // ---- layer 2 (bf16 uint2 gather + LDS pooling) ----
    k_g2  <<<gN2, 256, 0, stream>>>(csr, row_start, deg, (const uint2*)Ah, dis, b2, batch, pooled, N);

    // ---- head ----
    k_head<<<(G_GRAPHS + 255) / 256, 256, 0, stream>>>(pooled, Wl, bl, out);
}